// Round 2
// baseline (2574.542 us; speedup 1.0000x reference)
//
#include <hip/hip_runtime.h>
#include <cstdint>
#include <cstddef>

// CausalTransformer on MI355X — round 1 (resubmit of round-0 baseline; both
// prior rounds failed on infra before compiling/running).
// bf16-MFMA GEMMs (m97-style 128x128xBK64, global_load_lds), flash attention,
// fused epilogues. Workspace use ~68.2 MB.

#define AS1 __attribute__((address_space(1)))
#define AS3 __attribute__((address_space(3)))

typedef unsigned short u16;
typedef __bf16 bf16x8v __attribute__((ext_vector_type(8)));
typedef unsigned short u16x8 __attribute__((ext_vector_type(8)));
typedef unsigned short u16x4 __attribute__((ext_vector_type(4)));
typedef float f32x4 __attribute__((ext_vector_type(4)));

__device__ __forceinline__ u16 f2b(float f) {
  union { float f; unsigned u; } x; x.f = f;
  unsigned r = x.u + 0x7FFFu + ((x.u >> 16) & 1u);
  return (u16)(r >> 16);
}

// ---------------- fp32 -> bf16 convert ----------------
__global__ __launch_bounds__(256) void k_convert(const float* __restrict__ src,
                                                 u16* __restrict__ dst, int n8) {
  int i = blockIdx.x * 256 + threadIdx.x;
  if (i >= n8) return;
  const float4* s4 = (const float4*)src;
  float4 a = s4[2 * i], b = s4[2 * i + 1];
  u16x8 r;
  r[0] = f2b(a.x); r[1] = f2b(a.y); r[2] = f2b(a.z); r[3] = f2b(a.w);
  r[4] = f2b(b.x); r[5] = f2b(b.y); r[6] = f2b(b.z); r[7] = f2b(b.w);
  *(u16x8*)(dst + (size_t)i * 8) = r;
}

// ---------------- row LayerNorm (block per row) ----------------
// in: fp32 [rows][C]; writes fp32 (outf) and/or bf16 (outb), either may be null.
__global__ __launch_bounds__(256) void k_ln(const float* __restrict__ in,
                                            const float* __restrict__ gw,
                                            const float* __restrict__ bw,
                                            float* outf, u16* outb,
                                            int C, float eps) {
  int row = blockIdx.x, tid = threadIdx.x;
  int nv = C >> 2;
  const float4* in4 = (const float4*)(in + (size_t)row * C);
  float4 c0 = {0, 0, 0, 0}, c1 = {0, 0, 0, 0};
  float s1 = 0.f, s2 = 0.f;
  int cnt = 0;
  for (int i = tid; i < nv; i += 256) {
    float4 t = in4[i];
    if (cnt == 0) c0 = t; else c1 = t;
    cnt++;
    s1 += t.x + t.y + t.z + t.w;
    s2 += t.x * t.x + t.y * t.y + t.z * t.z + t.w * t.w;
  }
  __shared__ float red[8];
  for (int m = 32; m >= 1; m >>= 1) { s1 += __shfl_down(s1, m); s2 += __shfl_down(s2, m); }
  int wave = tid >> 6, lane = tid & 63;
  if (lane == 0) { red[wave * 2] = s1; red[wave * 2 + 1] = s2; }
  __syncthreads();
  s1 = red[0] + red[2] + red[4] + red[6];
  s2 = red[1] + red[3] + red[5] + red[7];
  float invC = 1.f / (float)C;
  float mean = s1 * invC;
  float var = s2 * invC - mean * mean;
  float rstd = rsqrtf(var + eps);
  const float4* g4 = (const float4*)gw;
  const float4* b4 = (const float4*)bw;
  cnt = 0;
  for (int i = tid; i < nv; i += 256) {
    float4 t = (cnt == 0) ? c0 : c1; cnt++;
    float4 gg = g4[i], bb = b4[i];
    float4 y;
    y.x = (t.x - mean) * rstd * gg.x + bb.x;
    y.y = (t.y - mean) * rstd * gg.y + bb.y;
    y.z = (t.z - mean) * rstd * gg.z + bb.z;
    y.w = (t.w - mean) * rstd * gg.w + bb.w;
    if (outf) *(float4*)(outf + (size_t)row * C + 4 * i) = y;
    if (outb) {
      u16x4 o;
      o[0] = f2b(y.x); o[1] = f2b(y.y); o[2] = f2b(y.z); o[3] = f2b(y.w);
      *(u16x4*)(outb + (size_t)row * C + 4 * i) = o;
    }
  }
}

// ---------------- bf16 GEMM: C = A(MxK) * B(NxK)^T + bias, fused epilogues ----
// 128x128 tile, BK=64, 4 waves, mfma 16x16x32_bf16, global_load_lds staging.
#define EPI_F32 0   // outf[m*Nout+n] = acc + bias            (n < Nout guard)
#define EPI_QKV 1   // outb = bf16(acc + bias), cols<1024 scaled by 0.125
#define EPI_RES 2   // outf = resid + acc + bias
#define EPI_GELU 3  // outb = bf16(gelu(acc + bias))

template <int EPI>
__global__ __launch_bounds__(256) void k_gemm(const u16* __restrict__ A,
                                              const u16* __restrict__ B,
                                              const float* __restrict__ bias,
                                              const float* resid,
                                              float* outf, u16* outb,
                                              int K, int Nout) {
  int tid = threadIdx.x, wave = tid >> 6, lane = tid & 63;
  int n0 = blockIdx.x * 128, m0 = blockIdx.y * 128;
  __shared__ u16 As[128 * 64];
  __shared__ u16 Bs[128 * 64];
  f32x4 acc[4][4] = {};
  int wm = (wave >> 1) * 64, wn = (wave & 1) * 64;
  int cl = lane & 15, grp = lane >> 4;

  for (int k0 = 0; k0 < K; k0 += 64) {
#pragma unroll
    for (int i = 0; i < 4; i++) {
      int o = ((i * 4 + wave) << 10) + lane * 16;  // byte offset in 16KB tile
      int row = o >> 7, col = (o & 127) >> 1;
      const u16* ga = A + (size_t)(m0 + row) * K + k0 + col;
      __builtin_amdgcn_global_load_lds((const AS1 void*)ga,
                                       (AS3 void*)(As + ((i * 4 + wave) << 9)),
                                       16, 0, 0);
      int rb = n0 + row;
      if (rb > Nout - 1) rb = Nout - 1;  // head-gemm OOB row clamp
      const u16* gb = B + (size_t)rb * K + k0 + col;
      __builtin_amdgcn_global_load_lds((const AS1 void*)gb,
                                       (AS3 void*)(Bs + ((i * 4 + wave) << 9)),
                                       16, 0, 0);
    }
    __syncthreads();
    bf16x8v a[4][2], b[4][2];
#pragma unroll
    for (int mf = 0; mf < 4; mf++)
#pragma unroll
      for (int kc = 0; kc < 2; kc++)
        a[mf][kc] = *(const bf16x8v*)(As + (wm + mf * 16 + cl) * 64 + kc * 32 + (grp << 3));
#pragma unroll
    for (int nf = 0; nf < 4; nf++)
#pragma unroll
      for (int kc = 0; kc < 2; kc++)
        b[nf][kc] = *(const bf16x8v*)(Bs + (wn + nf * 16 + cl) * 64 + kc * 32 + (grp << 3));
#pragma unroll
    for (int kc = 0; kc < 2; kc++)
#pragma unroll
      for (int mf = 0; mf < 4; mf++)
#pragma unroll
        for (int nf = 0; nf < 4; nf++)
          acc[mf][nf] = __builtin_amdgcn_mfma_f32_16x16x32_bf16(
              a[mf][kc], b[nf][kc], acc[mf][nf], 0, 0, 0);
    __syncthreads();
  }

#pragma unroll
  for (int nf = 0; nf < 4; nf++) {
    int gn = n0 + wn + nf * 16 + cl;
    bool nok = gn < Nout;
    float bv = nok ? bias[gn] : 0.f;
#pragma unroll
    for (int mf = 0; mf < 4; mf++)
#pragma unroll
      for (int r = 0; r < 4; r++) {
        int gm = m0 + wm + mf * 16 + grp * 4 + r;
        float v = acc[mf][nf][r] + bv;
        size_t oi = (size_t)gm * Nout + gn;
        if (EPI == EPI_F32) {
          if (nok) outf[oi] = v;
        } else if (EPI == EPI_RES) {
          if (nok) outf[oi] = resid[oi] + v;
        } else if (EPI == EPI_QKV) {
          if (gn < 1024) v *= 0.125f;  // fold 1/sqrt(64) into q, exact
          if (nok) outb[oi] = f2b(v);
        } else {  // EPI_GELU, exact gelu
          float gv = 0.5f * v * (1.f + erff(v * 0.70710678118654752f));
          if (nok) outb[oi] = f2b(gv);
        }
      }
  }
}

// ---------------- flash attention ----------------
// grid (16 qtiles, 32 bh). 4 waves; each wave owns 16 q-rows. KV tile = 64.
// qkv: bf16 [2048][3072] (q pre-scaled by 0.125). obuf: bf16 [2048][1024].
#define LSTR 72  // padded LDS stride (2-way banks)
__global__ __launch_bounds__(256) void k_attn(const u16* __restrict__ qkv,
                                              const float* __restrict__ rel_table,
                                              u16* __restrict__ obuf) {
  int tid = threadIdx.x, wave = tid >> 6, lane = tid & 63;
  int qt = blockIdx.x, bh = blockIdx.y;
  int bb = bh >> 4, h = bh & 15;
  __shared__ u16 Qs[64 * LSTR], Ks[64 * LSTR], Vs[64 * LSTR];  // Vs: [d][key]
  __shared__ u16 Ps[4][16 * LSTR];
  __shared__ float rels[257];
  for (int i = tid; i < 257; i += 256) rels[i] = rel_table[h * 257 + i];
  int tokb = bb * 1024, qb = qt * 64;
  {
    int r = tid >> 2, c0 = (tid & 3) * 16;
    const u16* src = qkv + (size_t)(tokb + qb + r) * 3072 + h * 64 + c0;
    *(u16x8*)&Qs[r * LSTR + c0] = *(const u16x8*)src;
    *(u16x8*)&Qs[r * LSTR + c0 + 8] = *(const u16x8*)(src + 8);
  }
  __syncthreads();
  int cl = lane & 15, grp = lane >> 4;
  bf16x8v aq[2];
#pragma unroll
  for (int kc = 0; kc < 2; kc++)
    aq[kc] = *(const bf16x8v*)&Qs[(wave * 16 + cl) * LSTR + kc * 32 + (grp << 3)];
  f32x4 oacc[4] = {};
  float mrun[4] = {-1e30f, -1e30f, -1e30f, -1e30f};
  float lrun[4] = {0.f, 0.f, 0.f, 0.f};

  for (int kt = 0; kt <= qt; kt++) {
    {
      int r = tid >> 2, c0 = (tid & 3) * 16;
      const u16* ks = qkv + (size_t)(tokb + kt * 64 + r) * 3072 + 1024 + h * 64 + c0;
      *(u16x8*)&Ks[r * LSTR + c0] = *(const u16x8*)ks;
      *(u16x8*)&Ks[r * LSTR + c0 + 8] = *(const u16x8*)(ks + 8);
      const u16* vs = qkv + (size_t)(tokb + kt * 64 + r) * 3072 + 2048 + h * 64 + c0;
      u16x8 v0 = *(const u16x8*)vs, v1 = *(const u16x8*)(vs + 8);
#pragma unroll
      for (int j = 0; j < 8; j++) {
        Vs[(c0 + j) * LSTR + r] = v0[j];
        Vs[(c0 + 8 + j) * LSTR + r] = v1[j];
      }
    }
    __syncthreads();
    // QK^T (q pre-scaled)
    f32x4 sc[4] = {};
#pragma unroll
    for (int nf = 0; nf < 4; nf++)
#pragma unroll
      for (int kc = 0; kc < 2; kc++) {
        bf16x8v bk = *(const bf16x8v*)&Ks[(nf * 16 + cl) * LSTR + kc * 32 + (grp << 3)];
        sc[nf] = __builtin_amdgcn_mfma_f32_16x16x32_bf16(aq[kc], bk, sc[nf], 0, 0, 0);
      }
    // rel-pos bias + causal mask
#pragma unroll
    for (int nf = 0; nf < 4; nf++) {
      int gk = kt * 64 + nf * 16 + cl;
#pragma unroll
      for (int r = 0; r < 4; r++) {
        int gq = qb + wave * 16 + grp * 4 + r;
        int d = gk - gq;
        int ci = (d < -128 ? -128 : (d > 128 ? 128 : d)) + 128;
        float bv = rels[ci];
        if (gk > gq) bv -= 1e9f;
        sc[nf][r] += bv;
      }
    }
    // online softmax per row (rows grp*4+r, shared across 16-lane group)
    float ps[4][4];
#pragma unroll
    for (int r = 0; r < 4; r++) {
      float rmax = fmaxf(fmaxf(sc[0][r], sc[1][r]), fmaxf(sc[2][r], sc[3][r]));
      rmax = fmaxf(rmax, __shfl_xor(rmax, 1));
      rmax = fmaxf(rmax, __shfl_xor(rmax, 2));
      rmax = fmaxf(rmax, __shfl_xor(rmax, 4));
      rmax = fmaxf(rmax, __shfl_xor(rmax, 8));
      float mnew = fmaxf(mrun[r], rmax);
      float alpha = __expf(mrun[r] - mnew);
      float psum = 0.f;
#pragma unroll
      for (int nf = 0; nf < 4; nf++) {
        float p = __expf(sc[nf][r] - mnew);
        ps[nf][r] = p;
        psum += p;
      }
      psum += __shfl_xor(psum, 1);
      psum += __shfl_xor(psum, 2);
      psum += __shfl_xor(psum, 4);
      psum += __shfl_xor(psum, 8);
      lrun[r] = lrun[r] * alpha + psum;
      mrun[r] = mnew;
#pragma unroll
      for (int nf = 0; nf < 4; nf++) oacc[nf][r] *= alpha;
    }
    // P -> LDS (bf16)
#pragma unroll
    for (int nf = 0; nf < 4; nf++)
#pragma unroll
      for (int r = 0; r < 4; r++)
        Ps[wave][(grp * 4 + r) * LSTR + nf * 16 + cl] = f2b(ps[nf][r]);
    __syncthreads();
    // PV
    bf16x8v ap[2];
#pragma unroll
    for (int kc = 0; kc < 2; kc++)
      ap[kc] = *(const bf16x8v*)&Ps[wave][cl * LSTR + kc * 32 + (grp << 3)];
#pragma unroll
    for (int nf = 0; nf < 4; nf++)
#pragma unroll
      for (int kc = 0; kc < 2; kc++) {
        bf16x8v bv = *(const bf16x8v*)&Vs[(nf * 16 + cl) * LSTR + kc * 32 + (grp << 3)];
        oacc[nf] = __builtin_amdgcn_mfma_f32_16x16x32_bf16(ap[kc], bv, oacc[nf], 0, 0, 0);
      }
    __syncthreads();
  }
#pragma unroll
  for (int r = 0; r < 4; r++) {
    float inv = 1.f / lrun[r];
    int gq = qb + wave * 16 + grp * 4 + r;
#pragma unroll
    for (int nf = 0; nf < 4; nf++)
      obuf[(size_t)(tokb + gq) * 1024 + h * 64 + nf * 16 + cl] = f2b(oacc[nf][r] * inv);
  }
}

// ---------------- launcher ----------------
extern "C" void kernel_launch(void* const* d_in, const int* in_sizes, int n_in,
                              void* d_out, int out_size, void* d_ws, size_t ws_size,
                              hipStream_t stream) {
  (void)in_sizes; (void)n_in; (void)out_size; (void)ws_size;
  const float* x        = (const float*)d_in[0];
  const float* pe_ln1_g = (const float*)d_in[1];
  const float* pe_ln1_b = (const float*)d_in[2];
  const float* pe_w     = (const float*)d_in[3];
  const float* pe_b     = (const float*)d_in[4];
  const float* pe_ln2_g = (const float*)d_in[5];
  const float* pe_ln2_b = (const float*)d_in[6];
  const float* lnA_g    = (const float*)d_in[7];
  const float* lnA_b    = (const float*)d_in[8];
  const float* qkv_w    = (const float*)d_in[9];
  const float* qkv_b    = (const float*)d_in[10];
  const float* out_w    = (const float*)d_in[11];
  const float* out_b    = (const float*)d_in[12];
  const float* lnF_g    = (const float*)d_in[13];
  const float* lnF_b    = (const float*)d_in[14];
  const float* fc1_w    = (const float*)d_in[15];
  const float* fc1_b    = (const float*)d_in[16];
  const float* fc2_w    = (const float*)d_in[17];
  const float* fc2_b    = (const float*)d_in[18];
  const float* rel      = (const float*)d_in[19];
  const float* fin_g    = (const float*)d_in[20];
  const float* fin_b    = (const float*)d_in[21];
  const float* head_w   = (const float*)d_in[22];
  const float* head_b   = (const float*)d_in[23];
  float* out = (float*)d_out;

  char* ws = (char*)d_ws;
  u16*   a_pe = (u16*)(ws);                      // 2048x1280 bf16   (5,242,880 B)
  float* z    = (float*)(ws + 5242880);          // 2048x1024 f32    (8,388,608 B)
  float* zpre = (float*)(ws + 13631488);         // 2048x1024 f32
  u16*   hbuf = (u16*)(ws + 22020096);           // 2048x1024 bf16
  u16*   qkvb = (u16*)(ws + 26214400);           // 2048x3072 bf16
  u16*   ob   = (u16*)(ws + 38797312);           // 2048x1024 bf16
  u16*   fbuf = (u16*)(ws + 42991616);           // 2048x4096 bf16
  u16*   wbuf = (u16*)(ws + 59768832);           // weight slab, 8,388,608 B
  // total 68,157,440 B

  auto conv = [&](const float* s, int n) {
    k_convert<<<dim3((n / 8 + 255) / 256), dim3(256), 0, stream>>>(s, wbuf, n / 8);
  };

  // patch embed
  conv(pe_w, 1280 * 1024);
  k_ln<<<2048, 256, 0, stream>>>(x, pe_ln1_g, pe_ln1_b, nullptr, a_pe, 1280, 1e-6f);
  k_gemm<EPI_F32><<<dim3(8, 16), 256, 0, stream>>>(a_pe, wbuf, pe_b, nullptr, zpre, nullptr, 1280, 1024);
  k_ln<<<2048, 256, 0, stream>>>(zpre, pe_ln2_g, pe_ln2_b, z, nullptr, 1024, 1e-6f);

  for (int l = 0; l < 8; l++) {
    k_ln<<<2048, 256, 0, stream>>>(z, lnA_g + l * 1024, lnA_b + l * 1024, nullptr, hbuf, 1024, 1e-5f);
    conv(qkv_w + (size_t)l * 3145728, 3145728);
    k_gemm<EPI_QKV><<<dim3(24, 16), 256, 0, stream>>>(hbuf, wbuf, qkv_b + l * 3072, nullptr, nullptr, qkvb, 1024, 3072);
    k_attn<<<dim3(16, 32), 256, 0, stream>>>(qkvb, rel, ob);
    conv(out_w + (size_t)l * 1048576, 1048576);
    k_gemm<EPI_RES><<<dim3(8, 16), 256, 0, stream>>>(ob, wbuf, out_b + l * 1024, z, z, nullptr, 1024, 1024);
    k_ln<<<2048, 256, 0, stream>>>(z, lnF_g + l * 1024, lnF_b + l * 1024, nullptr, hbuf, 1024, 1e-5f);
    conv(fc1_w + (size_t)l * 4194304, 4194304);
    k_gemm<EPI_GELU><<<dim3(32, 16), 256, 0, stream>>>(hbuf, wbuf, fc1_b + l * 4096, nullptr, nullptr, fbuf, 1024, 4096);
    conv(fc2_w + (size_t)l * 4194304, 4194304);
    k_gemm<EPI_RES><<<dim3(8, 16), 256, 0, stream>>>(fbuf, wbuf, fc2_b + l * 1024, z, z, nullptr, 4096, 1024);
  }

  k_ln<<<2048, 256, 0, stream>>>(z, fin_g, fin_b, nullptr, hbuf, 1024, 1e-5f);
  conv(head_w, 102400);
  k_gemm<EPI_F32><<<dim3(1, 16), 256, 0, stream>>>(hbuf, wbuf, head_b, nullptr, out, nullptr, 1024, 100);
}

// Round 3
// 2159.807 us; speedup vs baseline: 1.1920x; 1.1920x over previous
//
#include <hip/hip_runtime.h>
#include <cstdint>
#include <cstddef>

// CausalTransformer on MI355X — round 2.
// Change vs round 1: split-K (gridDim.z) + fp32 atomicAdd accumulation for the
// grid-starved N=1024 GEMMs (OUT, FC2) and PE/head; merged weight converts.
// Theory: FC2 at grid=128 blocks left half the chip idle (Occupancy 5.4%,
// MfmaUtil 6.7%). Split-K x4 -> 512 blocks (2/CU).

#define AS1 __attribute__((address_space(1)))
#define AS3 __attribute__((address_space(3)))

typedef unsigned short u16;
typedef __bf16 bf16x8v __attribute__((ext_vector_type(8)));
typedef unsigned short u16x8 __attribute__((ext_vector_type(8)));
typedef unsigned short u16x4 __attribute__((ext_vector_type(4)));
typedef float f32x4 __attribute__((ext_vector_type(4)));

__device__ __forceinline__ u16 f2b(float f) {
  union { float f; unsigned u; } x; x.f = f;
  unsigned r = x.u + 0x7FFFu + ((x.u >> 16) & 1u);
  return (u16)(r >> 16);
}

// ---------------- fp32 -> bf16 convert ----------------
__global__ __launch_bounds__(256) void k_convert(const float* __restrict__ src,
                                                 u16* __restrict__ dst, int n8) {
  int i = blockIdx.x * 256 + threadIdx.x;
  if (i >= n8) return;
  const float4* s4 = (const float4*)src;
  float4 a = s4[2 * i], b = s4[2 * i + 1];
  u16x8 r;
  r[0] = f2b(a.x); r[1] = f2b(a.y); r[2] = f2b(a.z); r[3] = f2b(a.w);
  r[4] = f2b(b.x); r[5] = f2b(b.y); r[6] = f2b(b.z); r[7] = f2b(b.w);
  *(u16x8*)(dst + (size_t)i * 8) = r;
}

// two-segment convert (one dispatch for two weight tensors)
__global__ __launch_bounds__(256) void k_convert2(const float* __restrict__ s0,
                                                  u16* __restrict__ d0, int n8_0,
                                                  const float* __restrict__ s1,
                                                  u16* __restrict__ d1, int n8_1) {
  int i = blockIdx.x * 256 + threadIdx.x;
  const float* s; u16* d; int j;
  if (i < n8_0) { s = s0; d = d0; j = i; }
  else { j = i - n8_0; if (j >= n8_1) return; s = s1; d = d1; }
  const float4* s4 = (const float4*)s;
  float4 a = s4[2 * j], b = s4[2 * j + 1];
  u16x8 r;
  r[0] = f2b(a.x); r[1] = f2b(a.y); r[2] = f2b(a.z); r[3] = f2b(a.w);
  r[4] = f2b(b.x); r[5] = f2b(b.y); r[6] = f2b(b.z); r[7] = f2b(b.w);
  *(u16x8*)(d + (size_t)j * 8) = r;
}

// ---------------- bias broadcast init (for split-K fresh outputs) ----------
__global__ __launch_bounds__(256) void k_bias_init(float* __restrict__ out,
                                                   const float* __restrict__ bias,
                                                   int N, int total4) {
  int i = blockIdx.x * 256 + threadIdx.x;
  if (i >= total4) return;
  int n = (i * 4) % N;
  *(float4*)(out + (size_t)i * 4) = *(const float4*)(bias + n);
}

// ---------------- row LayerNorm (block per row) ----------------
__global__ __launch_bounds__(256) void k_ln(const float* __restrict__ in,
                                            const float* __restrict__ gw,
                                            const float* __restrict__ bw,
                                            float* outf, u16* outb,
                                            int C, float eps) {
  int row = blockIdx.x, tid = threadIdx.x;
  int nv = C >> 2;
  const float4* in4 = (const float4*)(in + (size_t)row * C);
  float4 c0 = {0, 0, 0, 0}, c1 = {0, 0, 0, 0};
  float s1 = 0.f, s2 = 0.f;
  int cnt = 0;
  for (int i = tid; i < nv; i += 256) {
    float4 t = in4[i];
    if (cnt == 0) c0 = t; else c1 = t;
    cnt++;
    s1 += t.x + t.y + t.z + t.w;
    s2 += t.x * t.x + t.y * t.y + t.z * t.z + t.w * t.w;
  }
  __shared__ float red[8];
  for (int m = 32; m >= 1; m >>= 1) { s1 += __shfl_down(s1, m); s2 += __shfl_down(s2, m); }
  int wave = tid >> 6, lane = tid & 63;
  if (lane == 0) { red[wave * 2] = s1; red[wave * 2 + 1] = s2; }
  __syncthreads();
  s1 = red[0] + red[2] + red[4] + red[6];
  s2 = red[1] + red[3] + red[5] + red[7];
  float invC = 1.f / (float)C;
  float mean = s1 * invC;
  float var = s2 * invC - mean * mean;
  float rstd = rsqrtf(var + eps);
  const float4* g4 = (const float4*)gw;
  const float4* b4 = (const float4*)bw;
  cnt = 0;
  for (int i = tid; i < nv; i += 256) {
    float4 t = (cnt == 0) ? c0 : c1; cnt++;
    float4 gg = g4[i], bb = b4[i];
    float4 y;
    y.x = (t.x - mean) * rstd * gg.x + bb.x;
    y.y = (t.y - mean) * rstd * gg.y + bb.y;
    y.z = (t.z - mean) * rstd * gg.z + bb.z;
    y.w = (t.w - mean) * rstd * gg.w + bb.w;
    if (outf) *(float4*)(outf + (size_t)row * C + 4 * i) = y;
    if (outb) {
      u16x4 o;
      o[0] = f2b(y.x); o[1] = f2b(y.y); o[2] = f2b(y.z); o[3] = f2b(y.w);
      *(u16x4*)(outb + (size_t)row * C + 4 * i) = o;
    }
  }
}

// ---------------- bf16 GEMM: C = A(MxK) * B(NxK)^T, fused epilogues ----
// 128x128 tile, BK=64, 4 waves, mfma 16x16x32_bf16, global_load_lds staging.
// Split-K via gridDim.z: block computes K-range [z*Kc, (z+1)*Kc).
#define EPI_QKV 1   // outb = bf16(acc + bias), cols<1024 scaled by 0.125
#define EPI_GELU 3  // outb = bf16(gelu(acc + bias))
#define EPI_ATOM 4  // unsafeAtomicAdd(outf, acc + (z==0 && bias ? bias : 0))

template <int EPI>
__global__ __launch_bounds__(256) void k_gemm(const u16* __restrict__ A,
                                              const u16* __restrict__ B,
                                              const float* __restrict__ bias,
                                              float* outf, u16* outb,
                                              int Kstride, int Kc, int Nout) {
  int tid = threadIdx.x, wave = tid >> 6, lane = tid & 63;
  int n0 = blockIdx.x * 128, m0 = blockIdx.y * 128;
  int kbeg = blockIdx.z * Kc, kend = kbeg + Kc;
  __shared__ u16 As[128 * 64];
  __shared__ u16 Bs[128 * 64];
  f32x4 acc[4][4] = {};
  int wm = (wave >> 1) * 64, wn = (wave & 1) * 64;
  int cl = lane & 15, grp = lane >> 4;

  for (int k0 = kbeg; k0 < kend; k0 += 64) {
#pragma unroll
    for (int i = 0; i < 4; i++) {
      int o = ((i * 4 + wave) << 10) + lane * 16;  // byte offset in 16KB tile
      int row = o >> 7, col = (o & 127) >> 1;
      const u16* ga = A + (size_t)(m0 + row) * Kstride + k0 + col;
      __builtin_amdgcn_global_load_lds((const AS1 void*)ga,
                                       (AS3 void*)(As + ((i * 4 + wave) << 9)),
                                       16, 0, 0);
      int rb = n0 + row;
      if (rb > Nout - 1) rb = Nout - 1;  // head-gemm OOB row clamp
      const u16* gb = B + (size_t)rb * Kstride + k0 + col;
      __builtin_amdgcn_global_load_lds((const AS1 void*)gb,
                                       (AS3 void*)(Bs + ((i * 4 + wave) << 9)),
                                       16, 0, 0);
    }
    __syncthreads();
    bf16x8v a[4][2], b[4][2];
#pragma unroll
    for (int mf = 0; mf < 4; mf++)
#pragma unroll
      for (int kc = 0; kc < 2; kc++)
        a[mf][kc] = *(const bf16x8v*)(As + (wm + mf * 16 + cl) * 64 + kc * 32 + (grp << 3));
#pragma unroll
    for (int nf = 0; nf < 4; nf++)
#pragma unroll
      for (int kc = 0; kc < 2; kc++)
        b[nf][kc] = *(const bf16x8v*)(Bs + (wn + nf * 16 + cl) * 64 + kc * 32 + (grp << 3));
#pragma unroll
    for (int kc = 0; kc < 2; kc++)
#pragma unroll
      for (int mf = 0; mf < 4; mf++)
#pragma unroll
        for (int nf = 0; nf < 4; nf++)
          acc[mf][nf] = __builtin_amdgcn_mfma_f32_16x16x32_bf16(
              a[mf][kc], b[nf][kc], acc[mf][nf], 0, 0, 0);
    __syncthreads();
  }

  bool addb = (EPI != EPI_ATOM) || (blockIdx.z == 0 && bias != nullptr);
#pragma unroll
  for (int nf = 0; nf < 4; nf++) {
    int gn = n0 + wn + nf * 16 + cl;
    bool nok = gn < Nout;
    float bv = (nok && addb) ? bias[gn] : 0.f;
#pragma unroll
    for (int mf = 0; mf < 4; mf++)
#pragma unroll
      for (int r = 0; r < 4; r++) {
        int gm = m0 + wm + mf * 16 + grp * 4 + r;
        float v = acc[mf][nf][r] + bv;
        size_t oi = (size_t)gm * Nout + gn;
        if (EPI == EPI_ATOM) {
          if (nok) unsafeAtomicAdd(&outf[oi], v);
        } else if (EPI == EPI_QKV) {
          if (gn < 1024) v *= 0.125f;  // fold 1/sqrt(64) into q, exact
          if (nok) outb[oi] = f2b(v);
        } else {  // EPI_GELU, exact gelu
          float gv = 0.5f * v * (1.f + erff(v * 0.70710678118654752f));
          if (nok) outb[oi] = f2b(gv);
        }
      }
  }
}

// ---------------- flash attention ----------------
// grid (16 qtiles, 32 bh). 4 waves; each wave owns 16 q-rows. KV tile = 64.
#define LSTR 72  // padded LDS stride (2-way banks)
__global__ __launch_bounds__(256) void k_attn(const u16* __restrict__ qkv,
                                              const float* __restrict__ rel_table,
                                              u16* __restrict__ obuf) {
  int tid = threadIdx.x, wave = tid >> 6, lane = tid & 63;
  int qt = blockIdx.x, bh = blockIdx.y;
  int bb = bh >> 4, h = bh & 15;
  __shared__ u16 Qs[64 * LSTR], Ks[64 * LSTR], Vs[64 * LSTR];  // Vs: [d][key]
  __shared__ u16 Ps[4][16 * LSTR];
  __shared__ float rels[257];
  for (int i = tid; i < 257; i += 256) rels[i] = rel_table[h * 257 + i];
  int tokb = bb * 1024, qb = qt * 64;
  {
    int r = tid >> 2, c0 = (tid & 3) * 16;
    const u16* src = qkv + (size_t)(tokb + qb + r) * 3072 + h * 64 + c0;
    *(u16x8*)&Qs[r * LSTR + c0] = *(const u16x8*)src;
    *(u16x8*)&Qs[r * LSTR + c0 + 8] = *(const u16x8*)(src + 8);
  }
  __syncthreads();
  int cl = lane & 15, grp = lane >> 4;
  bf16x8v aq[2];
#pragma unroll
  for (int kc = 0; kc < 2; kc++)
    aq[kc] = *(const bf16x8v*)&Qs[(wave * 16 + cl) * LSTR + kc * 32 + (grp << 3)];
  f32x4 oacc[4] = {};
  float mrun[4] = {-1e30f, -1e30f, -1e30f, -1e30f};
  float lrun[4] = {0.f, 0.f, 0.f, 0.f};

  for (int kt = 0; kt <= qt; kt++) {
    {
      int r = tid >> 2, c0 = (tid & 3) * 16;
      const u16* ks = qkv + (size_t)(tokb + kt * 64 + r) * 3072 + 1024 + h * 64 + c0;
      *(u16x8*)&Ks[r * LSTR + c0] = *(const u16x8*)ks;
      *(u16x8*)&Ks[r * LSTR + c0 + 8] = *(const u16x8*)(ks + 8);
      const u16* vs = qkv + (size_t)(tokb + kt * 64 + r) * 3072 + 2048 + h * 64 + c0;
      u16x8 v0 = *(const u16x8*)vs, v1 = *(const u16x8*)(vs + 8);
#pragma unroll
      for (int j = 0; j < 8; j++) {
        Vs[(c0 + j) * LSTR + r] = v0[j];
        Vs[(c0 + 8 + j) * LSTR + r] = v1[j];
      }
    }
    __syncthreads();
    f32x4 sc[4] = {};
#pragma unroll
    for (int nf = 0; nf < 4; nf++)
#pragma unroll
      for (int kc = 0; kc < 2; kc++) {
        bf16x8v bk = *(const bf16x8v*)&Ks[(nf * 16 + cl) * LSTR + kc * 32 + (grp << 3)];
        sc[nf] = __builtin_amdgcn_mfma_f32_16x16x32_bf16(aq[kc], bk, sc[nf], 0, 0, 0);
      }
#pragma unroll
    for (int nf = 0; nf < 4; nf++) {
      int gk = kt * 64 + nf * 16 + cl;
#pragma unroll
      for (int r = 0; r < 4; r++) {
        int gq = qb + wave * 16 + grp * 4 + r;
        int d = gk - gq;
        int ci = (d < -128 ? -128 : (d > 128 ? 128 : d)) + 128;
        float bv = rels[ci];
        if (gk > gq) bv -= 1e9f;
        sc[nf][r] += bv;
      }
    }
    float ps[4][4];
#pragma unroll
    for (int r = 0; r < 4; r++) {
      float rmax = fmaxf(fmaxf(sc[0][r], sc[1][r]), fmaxf(sc[2][r], sc[3][r]));
      rmax = fmaxf(rmax, __shfl_xor(rmax, 1));
      rmax = fmaxf(rmax, __shfl_xor(rmax, 2));
      rmax = fmaxf(rmax, __shfl_xor(rmax, 4));
      rmax = fmaxf(rmax, __shfl_xor(rmax, 8));
      float mnew = fmaxf(mrun[r], rmax);
      float alpha = __expf(mrun[r] - mnew);
      float psum = 0.f;
#pragma unroll
      for (int nf = 0; nf < 4; nf++) {
        float p = __expf(sc[nf][r] - mnew);
        ps[nf][r] = p;
        psum += p;
      }
      psum += __shfl_xor(psum, 1);
      psum += __shfl_xor(psum, 2);
      psum += __shfl_xor(psum, 4);
      psum += __shfl_xor(psum, 8);
      lrun[r] = lrun[r] * alpha + psum;
      mrun[r] = mnew;
#pragma unroll
      for (int nf = 0; nf < 4; nf++) oacc[nf][r] *= alpha;
    }
#pragma unroll
    for (int nf = 0; nf < 4; nf++)
#pragma unroll
      for (int r = 0; r < 4; r++)
        Ps[wave][(grp * 4 + r) * LSTR + nf * 16 + cl] = f2b(ps[nf][r]);
    __syncthreads();
    bf16x8v ap[2];
#pragma unroll
    for (int kc = 0; kc < 2; kc++)
      ap[kc] = *(const bf16x8v*)&Ps[wave][cl * LSTR + kc * 32 + (grp << 3)];
#pragma unroll
    for (int nf = 0; nf < 4; nf++)
#pragma unroll
      for (int kc = 0; kc < 2; kc++) {
        bf16x8v bv = *(const bf16x8v*)&Vs[(nf * 16 + cl) * LSTR + kc * 32 + (grp << 3)];
        oacc[nf] = __builtin_amdgcn_mfma_f32_16x16x32_bf16(ap[kc], bv, oacc[nf], 0, 0, 0);
      }
    __syncthreads();
  }
#pragma unroll
  for (int r = 0; r < 4; r++) {
    float inv = 1.f / lrun[r];
    int gq = qb + wave * 16 + grp * 4 + r;
#pragma unroll
    for (int nf = 0; nf < 4; nf++)
      obuf[(size_t)(tokb + gq) * 1024 + h * 64 + nf * 16 + cl] = f2b(oacc[nf][r] * inv);
  }
}

// ---------------- launcher ----------------
extern "C" void kernel_launch(void* const* d_in, const int* in_sizes, int n_in,
                              void* d_out, int out_size, void* d_ws, size_t ws_size,
                              hipStream_t stream) {
  (void)in_sizes; (void)n_in; (void)out_size; (void)ws_size;
  const float* x        = (const float*)d_in[0];
  const float* pe_ln1_g = (const float*)d_in[1];
  const float* pe_ln1_b = (const float*)d_in[2];
  const float* pe_w     = (const float*)d_in[3];
  const float* pe_b     = (const float*)d_in[4];
  const float* pe_ln2_g = (const float*)d_in[5];
  const float* pe_ln2_b = (const float*)d_in[6];
  const float* lnA_g    = (const float*)d_in[7];
  const float* lnA_b    = (const float*)d_in[8];
  const float* qkv_w    = (const float*)d_in[9];
  const float* qkv_b    = (const float*)d_in[10];
  const float* out_w    = (const float*)d_in[11];
  const float* out_b    = (const float*)d_in[12];
  const float* lnF_g    = (const float*)d_in[13];
  const float* lnF_b    = (const float*)d_in[14];
  const float* fc1_w    = (const float*)d_in[15];
  const float* fc1_b    = (const float*)d_in[16];
  const float* fc2_w    = (const float*)d_in[17];
  const float* fc2_b    = (const float*)d_in[18];
  const float* rel      = (const float*)d_in[19];
  const float* fin_g    = (const float*)d_in[20];
  const float* fin_b    = (const float*)d_in[21];
  const float* head_w   = (const float*)d_in[22];
  const float* head_b   = (const float*)d_in[23];
  float* out = (float*)d_out;

  // workspace layout (62,914,560 B total; PE-only buffers alias fbuf):
  char* ws = (char*)d_ws;
  u16*   fbuf = (u16*)(ws);                      // 2048x4096 bf16  16,777,216 B
  u16*   a_pe = (u16*)(ws);                      //   (PE phase) 2048x1280 bf16
  float* zpre = (float*)(ws + 5242880);          //   (PE phase) 2048x1024 f32
  float* z    = (float*)(ws + 16777216);         // 2048x1024 f32    8,388,608 B
  u16*   hbuf = (u16*)(ws + 25165824);           // 2048x1024 bf16   4,194,304 B
  u16*   qkvb = (u16*)(ws + 29360128);           // 2048x3072 bf16  12,582,912 B
  u16*   ob   = (u16*)(ws + 41943040);           // 2048x1024 bf16   4,194,304 B
  u16*   wsl  = (u16*)(ws + 46137344);           // weight slab     16,777,216 B

  // patch embed: K=1280 split 4x320, accumulate into zpre (init = bias)
  k_convert<<<dim3(640), dim3(256), 0, stream>>>(pe_w, wsl, 163840);
  k_ln<<<2048, 256, 0, stream>>>(x, pe_ln1_g, pe_ln1_b, nullptr, a_pe, 1280, 1e-6f);
  k_bias_init<<<dim3(2048), dim3(256), 0, stream>>>(zpre, pe_b, 1024, 524288);
  k_gemm<EPI_ATOM><<<dim3(8, 16, 4), 256, 0, stream>>>(a_pe, wsl, nullptr, zpre, nullptr, 1280, 320, 1024);
  k_ln<<<2048, 256, 0, stream>>>(zpre, pe_ln2_g, pe_ln2_b, z, nullptr, 1024, 1e-6f);

  for (int l = 0; l < 8; l++) {
    u16* wq = wsl;                 // 3072x1024 bf16 (6 MB)
    u16* wo = wsl + 3145728;       // 1024x1024 bf16 (2 MB)
    u16* w1 = wsl;                 // 4096x1024 bf16 (8 MB)
    u16* w2 = wsl + 4194304;       // 1024x4096 bf16 (8 MB)
    k_ln<<<2048, 256, 0, stream>>>(z, lnA_g + l * 1024, lnA_b + l * 1024, nullptr, hbuf, 1024, 1e-5f);
    k_convert2<<<dim3(2048), dim3(256), 0, stream>>>(qkv_w + (size_t)l * 3145728, wq, 393216,
                                                     out_w + (size_t)l * 1048576, wo, 131072);
    k_gemm<EPI_QKV><<<dim3(24, 16, 1), 256, 0, stream>>>(hbuf, wq, qkv_b + l * 3072, nullptr, qkvb, 1024, 1024, 3072);
    k_attn<<<dim3(16, 32), 256, 0, stream>>>(qkvb, rel, ob);
    // OUT: K=1024 split 4x256, atomic into z (z already holds residual)
    k_gemm<EPI_ATOM><<<dim3(8, 16, 4), 256, 0, stream>>>(ob, wo, out_b + l * 1024, z, nullptr, 1024, 256, 1024);
    k_ln<<<2048, 256, 0, stream>>>(z, lnF_g + l * 1024, lnF_b + l * 1024, nullptr, hbuf, 1024, 1e-5f);
    k_convert2<<<dim3(4096), dim3(256), 0, stream>>>(fc1_w + (size_t)l * 4194304, w1, 524288,
                                                     fc2_w + (size_t)l * 4194304, w2, 524288);
    k_gemm<EPI_GELU><<<dim3(32, 16, 1), 256, 0, stream>>>(hbuf, w1, fc1_b + l * 4096, nullptr, fbuf, 1024, 1024, 4096);
    // FC2: K=4096 split 4x1024, atomic into z
    k_gemm<EPI_ATOM><<<dim3(8, 16, 4), 256, 0, stream>>>(fbuf, w2, fc2_b + l * 1024, z, nullptr, 4096, 1024, 1024);
  }

  k_ln<<<2048, 256, 0, stream>>>(z, fin_g, fin_b, nullptr, hbuf, 1024, 1e-5f);
  k_convert<<<dim3(50), dim3(256), 0, stream>>>(head_w, wsl, 12800);
  k_bias_init<<<dim3(200), dim3(256), 0, stream>>>(out, head_b, 100, 51200);
  k_gemm<EPI_ATOM><<<dim3(1, 16, 4), 256, 0, stream>>>(hbuf, wsl, nullptr, out, nullptr, 1024, 256, 100);
}